// Round 3
// baseline (708.881 us; speedup 1.0000x reference)
//
#include <hip/hip_runtime.h>
#include <hip/hip_bf16.h>

#define Hh 256
#define Ii 128
#define KF 384    // 128 (x) + 256 (hx) feature dim
#define LDSB 72   // sP padded stride (bf16 elems)
#define BK 192    // t-chunk per stage (2 chunks per phase)
#define SBST 200  // sB padded stride (bf16 elems)

typedef __attribute__((ext_vector_type(8))) short bf16x8;
typedef __attribute__((ext_vector_type(4))) float f32x4;
typedef unsigned short u16;
typedef unsigned int u32;

__device__ inline u16 f2bf(float f) {
  u32 u = __float_as_uint(f);
  u += 0x7FFFu + ((u >> 16) & 1u);   // RNE
  return (u16)(u >> 16);
}
__device__ inline u32 pack_bf16x2(float a, float b) {
  __hip_bfloat162 h = __float22bfloat162_rn(make_float2(a, b));
  u32 r; __builtin_memcpy(&r, &h, 4); return r;
}
// scale packed bf16 pair by (va, vb), repack
__device__ inline u32 scale2(u32 packed, float va, float vb) {
  float lo = __uint_as_float(packed << 16) * va;
  float hi = __uint_as_float(packed & 0xFFFF0000u) * vb;
  return pack_bf16x2(lo, hi);
}
__device__ inline float sigm(float x) { return 1.0f / (1.0f + __expf(-x)); }
__device__ inline float tanh_f(float x) { return 1.0f - 2.0f / (1.0f + __expf(2.0f * x)); }

// ---------------- kernel 0: pack weights, transpose Vtinv, pack Uinv --------
__global__ __launch_bounds__(256) void k_prep(
    const float* __restrict__ Wii, const float* __restrict__ Wif, const float* __restrict__ Wig,
    const float* __restrict__ Whi, const float* __restrict__ Whit,
    const float* __restrict__ Whf, const float* __restrict__ Whft,
    const float* __restrict__ Whc, const float* __restrict__ Whct,
    const float* __restrict__ Vtinv, const float* __restrict__ Uinv,
    u16* __restrict__ RW, u16* __restrict__ CW, u16* __restrict__ Vtt,
    float* __restrict__ UinvP, float* __restrict__ proj) {
  const int tid = threadIdx.x, bx = blockIdx.x, y = blockIdx.y;
  if (y < 3) {
    const float* WX  = (y == 0) ? Wii : (y == 1 ? Wif : Wig);
    const float* WHr = (y == 0) ? Whi : (y == 1 ? Whf : Whc);
    const float* WHt = (y == 0) ? Whit : (y == 1 ? Whft : Whct);
    u16* rw = RW + y * Hh * KF;
    u16* cw = CW + y * Hh * KF;
#pragma unroll
    for (int it = 0; it < 4; ++it) {
      int idx = it * 24576 + bx * 256 + tid;   // 0..98303
      int h = idx / KF, t = idx - h * KF;
      float a, c;
      if (t < Ii) { a = WX[h * Ii + t]; c = a; }
      else        { a = WHr[h * Hh + t - Ii]; c = WHt[h * Hh + t - Ii]; }
      rw[idx] = f2bf(a);
      cw[idx] = f2bf(c);
    }
  } else if (y == 3) {
    if (bx < 64) {
      // Vtt[i][k] = Vtinv[k][i], 32x32 LDS tile transpose
      __shared__ u16 tbuf[32][33];
      const int c = tid & 31, r8 = tid >> 5;
      const int tr = bx >> 3, tc = bx & 7;
#pragma unroll
      for (int rr = r8; rr < 32; rr += 8)
        tbuf[rr][c] = f2bf(Vtinv[(tc * 32 + rr) * Hh + tr * 32 + c]);
      __syncthreads();
#pragma unroll
      for (int rr = r8; rr < 32; rr += 8)
        Vtt[(tr * 32 + rr) * Hh + tc * 32 + c] = tbuf[c][rr];
    } else if (bx < 96) {
      const int base = (bx - 64) * 256 + tid;
      const float4 z = {0.f, 0.f, 0.f, 0.f};
#pragma unroll
      for (int it = 0; it < 4; ++it)
        *(float4*)(proj + (size_t)(it * 8192 + base) * 4) = z;
    }
  } else {
    // UinvP: f = tid512*128 + e ; e = ti*32 + tjl*4 + r
    if (bx < 32) {
      const int base = (bx * 256 + tid) * 8;
#pragma unroll
      for (int e8 = 0; e8 < 8; ++e8) {
        int f = base + e8;                  // 0..65535
        int t512 = f >> 7;
        int e = f & 127;
        int ti = e >> 5;
        int rem = e & 31;
        int tjl = rem >> 2;
        int rr = rem & 3;
        int wv = t512 >> 6;
        int ln = t512 & 63;
        int qd = ln >> 4;
        int r15v = ln & 15;
        int i = (wv & 3) * 64 + ti * 16 + qd * 4 + rr;
        int j = (wv >> 2) * 128 + tjl * 16 + r15v;
        UinvP[f] = Uinv[i * Hh + j];
      }
    }
  }
}

// ---------------- kernel 1: fused gates + cell + down-projection -------------
// grid 2048 = b(512) x kb(4); 512 threads = 8 waves = 4(j) x 2(k).
// Wave owns j-slab of 64 (wj) and k-half of 32 (wk): A-LDS redundancy 4x
// (was 8x), 32 MFMA per wave per 12 ds_read_b128.
// BK=192: 6 chunk-steps, ~9 barriers total (was 19).
// sP (projection c-tile) aliases the sB double-buffer via union: sB is dead
// after the final gate chunk's barrier, before the first sP write.
// NOTE: no min-waves launch_bounds arg (R1: (512,4) forced VGPR=64 + 2.2 GB
// scratch spill). Target VGPR <= 128 for 16 waves/CU.
__global__ __launch_bounds__(512) void k_main(
    const float* __restrict__ x, const float* __restrict__ hx, const float* __restrict__ cx,
    const u16* __restrict__ RW, const u16* __restrict__ CW, const u16* __restrict__ Vtt,
    const float* __restrict__ bi, const float* __restrict__ bfm, const float* __restrict__ bg,
    const float* __restrict__ UinvP, float* __restrict__ proj) {
  __shared__ union {
    u16 B[2][64][SBST];   // 51200 B scaled-A dbuf (64 k-rows x 192 t)
    u16 P[256][LDSB];     // 36864 B c-tile (256 j x 64 k)
  } sU;
  __shared__ float sV[KF];        // 1536 B
  __shared__ float sPart[8][64];  // 2048 B

  const int tid  = threadIdx.x;
  const int b    = blockIdx.x >> 2;
  const int kb   = blockIdx.x & 3;
  const int k0   = kb * 64;
  const int lane = tid & 63;
  const int w    = tid >> 6;
  const int wj   = w >> 1;            // j-slab 0..3 (64 rows each)
  const int wk   = w & 1;             // k-half 0..1 (32 cols each)
  const int r15  = lane & 15;
  const int quad = lane >> 4;
  const int srow = tid >> 3;          // staging row 0..63
  const int scg  = tid & 7;           // staging col group (24 elems each)

  if (tid < Ii) sV[tid] = x[b * Ii + tid];
  if (tid < Hh) sV[Ii + tid] = hx[b * Hh + tid];

  // phase order: g (tanh), i, f
  const u16* rwp[3] = {RW + 2 * Hh * KF, RW, RW + 1 * Hh * KF};
  const u16* cwp[3] = {CW + 2 * Hh * KF, CW, CW + 1 * Hh * KF};
  const float* bp3[3] = {bg, bi, bfm};
  const float* cx_b = cx + (size_t)b * Hh * Hh;

  // prologue: raw chunk 0 load (independent of sV)
  uint4 m0, m1, m2;
  {
    const u16* src = cwp[0] + (size_t)(k0 + srow) * KF + scg * 24;
    m0 = *(const uint4*)src;
    m1 = *(const uint4*)(src + 8);
    m2 = *(const uint4*)(src + 16);
  }
  __syncthreads();   // sV ready
  {
    const float* vp = &sV[scg * 24];
    const float4 v0 = *(const float4*)(vp);
    const float4 v1 = *(const float4*)(vp + 4);
    const float4 v2 = *(const float4*)(vp + 8);
    const float4 v3 = *(const float4*)(vp + 12);
    const float4 v4 = *(const float4*)(vp + 16);
    const float4 v5 = *(const float4*)(vp + 20);
    uint4 o0, o1, o2;
    o0.x = scale2(m0.x, v0.x, v0.y); o0.y = scale2(m0.y, v0.z, v0.w);
    o0.z = scale2(m0.z, v1.x, v1.y); o0.w = scale2(m0.w, v1.z, v1.w);
    o1.x = scale2(m1.x, v2.x, v2.y); o1.y = scale2(m1.y, v2.z, v2.w);
    o1.z = scale2(m1.z, v3.x, v3.y); o1.w = scale2(m1.w, v3.z, v3.w);
    o2.x = scale2(m2.x, v4.x, v4.y); o2.y = scale2(m2.y, v4.z, v4.w);
    o2.z = scale2(m2.z, v5.x, v5.y); o2.w = scale2(m2.w, v5.z, v5.w);
    u16* dst = &sU.B[0][srow][scg * 24];
    *(uint4*)dst = o0;
    *(uint4*)(dst + 8) = o1;
    *(uint4*)(dst + 16) = o2;
  }
  __syncthreads();   // sB[0] ready

  float p[4][2][4];
  f32x4 acc[4][2];
  const size_t jrow = (size_t)(wj * 64 + r15) * KF;
  const int ar = wk * 32 + r15;

#pragma unroll
  for (int ph = 0; ph < 3; ++ph) {
#pragma unroll
    for (int ja = 0; ja < 4; ++ja)
#pragma unroll
      for (int tk = 0; tk < 2; ++tk)
#pragma unroll
        for (int r = 0; r < 4; ++r) acc[ja][tk][r] = 0.0f;

#pragma unroll
    for (int kc = 0; kc < 2; ++kc) {
      const int sc  = ph * 2 + kc;
      const int cur = sc & 1;
      const int t0  = kc * BK;
      uint4 n0, n1, n2;
      if (sc < 5) {
        const int nsc = sc + 1;
        const int nph = nsc >> 1;
        const int nt0 = (nsc & 1) * BK;
        const u16* src = cwp[nph] + (size_t)(k0 + srow) * KF + nt0 + scg * 24;
        n0 = *(const uint4*)src;
        n1 = *(const uint4*)(src + 8);
        n2 = *(const uint4*)(src + 16);
      }
      const u16* rb = rwp[ph] + jrow + t0 + quad * 8;
#pragma unroll
      for (int ksl = 0; ksl < 6; ++ksl) {
        const bf16x8 sf0 = *(const bf16x8*)(&sU.B[cur][ar][ksl * 32 + quad * 8]);
        const bf16x8 sf1 = *(const bf16x8*)(&sU.B[cur][ar + 16][ksl * 32 + quad * 8]);
        const bf16x8 wf0 = *(const bf16x8*)(rb + ksl * 32);
        const bf16x8 wf1 = *(const bf16x8*)(rb + 16 * KF + ksl * 32);
        const bf16x8 wf2 = *(const bf16x8*)(rb + 32 * KF + ksl * 32);
        const bf16x8 wf3 = *(const bf16x8*)(rb + 48 * KF + ksl * 32);
        acc[0][0] = __builtin_amdgcn_mfma_f32_16x16x32_bf16(sf0, wf0, acc[0][0], 0, 0, 0);
        acc[0][1] = __builtin_amdgcn_mfma_f32_16x16x32_bf16(sf1, wf0, acc[0][1], 0, 0, 0);
        acc[1][0] = __builtin_amdgcn_mfma_f32_16x16x32_bf16(sf0, wf1, acc[1][0], 0, 0, 0);
        acc[1][1] = __builtin_amdgcn_mfma_f32_16x16x32_bf16(sf1, wf1, acc[1][1], 0, 0, 0);
        acc[2][0] = __builtin_amdgcn_mfma_f32_16x16x32_bf16(sf0, wf2, acc[2][0], 0, 0, 0);
        acc[2][1] = __builtin_amdgcn_mfma_f32_16x16x32_bf16(sf1, wf2, acc[2][1], 0, 0, 0);
        acc[3][0] = __builtin_amdgcn_mfma_f32_16x16x32_bf16(sf0, wf3, acc[3][0], 0, 0, 0);
        acc[3][1] = __builtin_amdgcn_mfma_f32_16x16x32_bf16(sf1, wf3, acc[3][1], 0, 0, 0);
      }
      if (sc < 5) {
        const int nsc = sc + 1;
        const int nt0 = (nsc & 1) * BK;
        const float* vp = &sV[nt0 + scg * 24];
        const float4 v0 = *(const float4*)(vp);
        const float4 v1 = *(const float4*)(vp + 4);
        const float4 v2 = *(const float4*)(vp + 8);
        const float4 v3 = *(const float4*)(vp + 12);
        const float4 v4 = *(const float4*)(vp + 16);
        const float4 v5 = *(const float4*)(vp + 20);
        uint4 o0, o1, o2;
        o0.x = scale2(n0.x, v0.x, v0.y); o0.y = scale2(n0.y, v0.z, v0.w);
        o0.z = scale2(n0.z, v1.x, v1.y); o0.w = scale2(n0.w, v1.z, v1.w);
        o1.x = scale2(n1.x, v2.x, v2.y); o1.y = scale2(n1.y, v2.z, v2.w);
        o1.z = scale2(n1.z, v3.x, v3.y); o1.w = scale2(n1.w, v3.z, v3.w);
        o2.x = scale2(n2.x, v4.x, v4.y); o2.y = scale2(n2.y, v4.z, v4.w);
        o2.z = scale2(n2.z, v5.x, v5.y); o2.w = scale2(n2.w, v5.z, v5.w);
        u16* dst = &sU.B[cur ^ 1][srow][scg * 24];
        *(uint4*)dst = o0;
        *(uint4*)(dst + 8) = o1;
        *(uint4*)(dst + 16) = o2;
      }
      if (ph < 2 && kc == 1) {
        // C layout: row(k) = k0 + wk*32 + tk*16 + quad*4 + r, col(j) = wj*64 + ja*16 + r15
        const float* bp = bp3[ph];
#pragma unroll
        for (int ja = 0; ja < 4; ++ja) {
          const int jg = wj * 64 + ja * 16 + r15;
          const float* bpr = bp + (size_t)jg * Hh + k0 + wk * 32 + quad * 4;
#pragma unroll
          for (int tk = 0; tk < 2; ++tk) {
            const float4 bv = *(const float4*)(bpr + tk * 16);
            if (ph == 0) {
#pragma unroll
              for (int r = 0; r < 4; ++r)
                p[ja][tk][r] = tanh_f(acc[ja][tk][r] + ((const float*)&bv)[r]);
            } else {
#pragma unroll
              for (int r = 0; r < 4; ++r)
                p[ja][tk][r] *= sigm(acc[ja][tk][r] + ((const float*)&bv)[r]);
            }
          }
        }
      }
      __syncthreads();
    }
  }

  // ---- ph2 combine (post final barrier: sU.B dead, safe to write sU.P) ----
#pragma unroll
  for (int ja = 0; ja < 4; ++ja) {
    const int jg = wj * 64 + ja * 16 + r15;
    const float* bpr = bfm + (size_t)jg * Hh + k0 + wk * 32 + quad * 4;
    const float* cxr = cx_b + (size_t)jg * Hh + k0 + wk * 32 + quad * 4;
#pragma unroll
    for (int tk = 0; tk < 2; ++tk) {
      const float4 bv = *(const float4*)(bpr + tk * 16);
      const float4 cv = *(const float4*)(cxr + tk * 16);
      float cc[4];
#pragma unroll
      for (int r = 0; r < 4; ++r)
        cc[r] = sigm(acc[ja][tk][r] + ((const float*)&bv)[r]) * ((const float*)&cv)[r] + p[ja][tk][r];
      uint2 pk;
      pk.x = pack_bf16x2(cc[0], cc[1]);
      pk.y = pack_bf16x2(cc[2], cc[3]);
      *(uint2*)(&sU.P[jg][wk * 32 + tk * 16 + quad * 4]) = pk;
    }
  }
  __syncthreads();

  // ---- projection: M[i,j] = sum_k Vtt[i,k] c[j,k]; racc[i] += M[i,j]*Uinv[i,j]
  //      wave: i-slab = (w&3)*64, j-half = (w>>2)*128 .. +128
  const int islab = (w & 3) * 64;
  const int jhb   = (w >> 2) * 128;
  const float* up = UinvP + (size_t)tid * 128;
  float racc[4][4];
#pragma unroll
  for (int ti = 0; ti < 4; ++ti)
#pragma unroll
    for (int r = 0; r < 4; ++r) racc[ti][r] = 0.0f;

#pragma unroll
  for (int tjg = 0; tjg < 2; ++tjg) {
    bf16x8 fbp[2][4];
#pragma unroll
    for (int ks = 0; ks < 2; ++ks)
#pragma unroll
      for (int tjj = 0; tjj < 4; ++tjj)
        fbp[ks][tjj] = *(const bf16x8*)(&sU.P[jhb + (tjg * 4 + tjj) * 16 + r15][ks * 32 + quad * 8]);
#pragma unroll
    for (int ti = 0; ti < 4; ++ti) {
      const u16* vrow = Vtt + (size_t)(islab + ti * 16 + r15) * Hh + k0 + quad * 8;
      const bf16x8 va0 = *(const bf16x8*)vrow;
      const bf16x8 va1 = *(const bf16x8*)(vrow + 32);
      f32x4 pacc[4];
#pragma unroll
      for (int tjj = 0; tjj < 4; ++tjj)
#pragma unroll
        for (int r = 0; r < 4; ++r) pacc[tjj][r] = 0.0f;
#pragma unroll
      for (int tjj = 0; tjj < 4; ++tjj)
        pacc[tjj] = __builtin_amdgcn_mfma_f32_16x16x32_bf16(va0, fbp[0][tjj], pacc[tjj], 0, 0, 0);
#pragma unroll
      for (int tjj = 0; tjj < 4; ++tjj)
        pacc[tjj] = __builtin_amdgcn_mfma_f32_16x16x32_bf16(va1, fbp[1][tjj], pacc[tjj], 0, 0, 0);
#pragma unroll
      for (int tjj = 0; tjj < 4; ++tjj) {
        const float4 uu = *(const float4*)(up + ti * 32 + (tjg * 4 + tjj) * 4);
#pragma unroll
        for (int r = 0; r < 4; ++r)
          racc[ti][r] += pacc[tjj][r] * ((const float*)&uu)[r];
      }
    }
  }

#pragma unroll
  for (int ti = 0; ti < 4; ++ti)
#pragma unroll
    for (int r = 0; r < 4; ++r) {
      float v = racc[ti][r];
      v += __shfl_xor(v, 1);
      v += __shfl_xor(v, 2);
      v += __shfl_xor(v, 4);
      v += __shfl_xor(v, 8);
      if (r15 == 0) sPart[w][ti * 16 + quad * 4 + r] = v;
    }
  __syncthreads();
  if (tid < Hh)
    atomicAdd(&proj[b * Hh + tid], sPart[tid >> 6][tid & 63] + sPart[(tid >> 6) + 4][tid & 63]);
}

// ---------------- kernel 2: o-gate + final output ---------------------------
__global__ __launch_bounds__(256) void k_out(
    const float* __restrict__ x, const float* __restrict__ hx,
    const float* __restrict__ Wio, const float* __restrict__ Who,
    const float* __restrict__ bo, const float* __restrict__ proj,
    float* __restrict__ out) {
  __shared__ float sv[KF];
  const int b = blockIdx.x, tid = threadIdx.x;
  const int lane = tid & 63, w = tid >> 6;
  if (tid < Ii) sv[tid] = x[b * Ii + tid];
  sv[Ii + tid] = hx[b * Hh + tid];
  __syncthreads();
  for (int rr = 0; rr < 64; ++rr) {
    const int h = w * 64 + rr;
    float p = Wio[h * Ii + lane]        * sv[lane]
            + Wio[h * Ii + 64 + lane]   * sv[64 + lane]
            + Who[h * Hh + lane]        * sv[128 + lane]
            + Who[h * Hh + 64 + lane]   * sv[192 + lane]
            + Who[h * Hh + 128 + lane]  * sv[256 + lane]
            + Who[h * Hh + 192 + lane]  * sv[320 + lane];
    p += __shfl_xor(p, 32);
    p += __shfl_xor(p, 16);
    p += __shfl_xor(p, 8);
    p += __shfl_xor(p, 4);
    p += __shfl_xor(p, 2);
    p += __shfl_xor(p, 1);
    if (lane == 0)
      out[b * Hh + h] = sigm(p + bo[h]) * sigm(proj[b * Hh + h]);
  }
}

extern "C" void kernel_launch(void* const* d_in, const int* in_sizes, int n_in,
                              void* d_out, int out_size, void* d_ws, size_t ws_size,
                              hipStream_t stream) {
  (void)in_sizes; (void)n_in; (void)out_size; (void)ws_size;
  const float* x    = (const float*)d_in[0];
  const float* hx   = (const float*)d_in[1];
  const float* cx   = (const float*)d_in[2];
  const float* Wii  = (const float*)d_in[3];
  const float* Wif  = (const float*)d_in[4];
  const float* Wig  = (const float*)d_in[5];
  const float* Wio  = (const float*)d_in[6];
  const float* Whi  = (const float*)d_in[7];
  const float* Whit = (const float*)d_in[8];
  const float* Whf  = (const float*)d_in[9];
  const float* Whft = (const float*)d_in[10];
  const float* Whc  = (const float*)d_in[11];
  const float* Whct = (const float*)d_in[12];
  const float* Who  = (const float*)d_in[13];
  const float* Uinv = (const float*)d_in[14];
  const float* Vtinv= (const float*)d_in[15];
  const float* bi   = (const float*)d_in[16];
  const float* bf   = (const float*)d_in[17];
  const float* bg   = (const float*)d_in[18];
  const float* bo   = (const float*)d_in[19];
  float* out = (float*)d_out;

  // workspace (~2.0 MB): RW[3], CW[3], Vtt (bf16); UinvP, proj (f32)
  u16* RW    = (u16*)d_ws;
  u16* CW    = RW + 3 * Hh * KF;
  u16* Vtt   = CW + 3 * Hh * KF;
  float* UinvP = (float*)(Vtt + Hh * Hh);
  float* proj  = UinvP + Hh * Hh;

  k_prep<<<dim3(96, 5), 256, 0, stream>>>(Wii, Wif, Wig, Whi, Whit, Whf, Whft, Whc, Whct,
                                          Vtinv, Uinv, RW, CW, Vtt, UinvP, proj);
  k_main<<<2048, 512, 0, stream>>>(x, hx, cx, RW, CW, Vtt, bi, bf, bg, UinvP, proj);
  k_out<<<512, 256, 0, stream>>>(x, hx, Wio, Who, bo, proj, out);
}

// Round 5
// 578.598 us; speedup vs baseline: 1.2252x; 1.2252x over previous
//
#include <hip/hip_runtime.h>
#include <hip/hip_bf16.h>

#define Hh 256
#define Ii 128
#define KF 384    // 128 (x) + 256 (hx) feature dim
#define LDSB 72   // padded LDS stride (bf16 elems)

typedef __attribute__((ext_vector_type(8))) short bf16x8;
typedef __attribute__((ext_vector_type(4))) float f32x4;
typedef unsigned short u16;
typedef unsigned int u32;

__device__ inline u16 f2bf(float f) {
  u32 u = __float_as_uint(f);
  u += 0x7FFFu + ((u >> 16) & 1u);   // RNE
  return (u16)(u >> 16);
}
__device__ inline u32 pack_bf16x2(float a, float b) {
  __hip_bfloat162 h = __float22bfloat162_rn(make_float2(a, b));
  u32 r; __builtin_memcpy(&r, &h, 4); return r;
}
// scale packed bf16 pair by (va, vb), repack
__device__ inline u32 scale2(u32 packed, float va, float vb) {
  float lo = __uint_as_float(packed << 16) * va;
  float hi = __uint_as_float(packed & 0xFFFF0000u) * vb;
  return pack_bf16x2(lo, hi);
}
__device__ inline float sigm(float x) { return 1.0f / (1.0f + __expf(-x)); }
__device__ inline float tanh_f(float x) { return 1.0f - 2.0f / (1.0f + __expf(2.0f * x)); }

union U32x4 { bf16x8 f; u32 d[4]; uint4 v; };

// ---------------- kernel 0: pack weights (CHUNK-MAJOR), transpose Vtinv -----
// RWp[ph][kc][j][64]        : ph*98304 + kc*16384 + j*64 + t'
// CWp[ph][kb][kc][k64][64]  : ph*98304 + kb*24576 + kc*4096 + k*64 + t'
// Chunk-major makes k_main's staging load one contiguous 8 KB block and the
// wf fragment loads cover consecutive fully-consumed 128B lines (R3 post-
// mortem: scattered 64B-of-768B-stride L2 requests were the top suspect).
__global__ __launch_bounds__(256) void k_prep(
    const float* __restrict__ Wii, const float* __restrict__ Wif, const float* __restrict__ Wig,
    const float* __restrict__ Whi, const float* __restrict__ Whit,
    const float* __restrict__ Whf, const float* __restrict__ Whft,
    const float* __restrict__ Whc, const float* __restrict__ Whct,
    const float* __restrict__ Vtinv, const float* __restrict__ Uinv,
    u16* __restrict__ RW, u16* __restrict__ CW, u16* __restrict__ Vtt,
    float* __restrict__ UinvP, float* __restrict__ proj) {
  const int tid = threadIdx.x, bx = blockIdx.x, y = blockIdx.y;
  if (y < 3) {
    const float* WX  = (y == 0) ? Wii : (y == 1 ? Wif : Wig);
    const float* WHr = (y == 0) ? Whi : (y == 1 ? Whf : Whc);
    const float* WHt = (y == 0) ? Whit : (y == 1 ? Whft : Whct);
    u16* rw = RW + y * Hh * KF;
    u16* cw = CW + y * Hh * KF;
#pragma unroll
    for (int it = 0; it < 4; ++it) {
      int idx = it * 24576 + bx * 256 + tid;   // 0..98303
      int h = idx / KF, t = idx - h * KF;
      float a, c;
      if (t < Ii) { a = WX[h * Ii + t]; c = a; }
      else        { a = WHr[h * Hh + t - Ii]; c = WHt[h * Hh + t - Ii]; }
      rw[(t >> 6) * 16384 + h * 64 + (t & 63)] = f2bf(a);
      cw[(h >> 6) * 24576 + (t >> 6) * 4096 + (h & 63) * 64 + (t & 63)] = f2bf(c);
    }
  } else if (y == 3) {
    if (bx < 64) {
      // Vtt[i][k] = Vtinv[k][i], 32x32 LDS tile transpose
      __shared__ u16 tbuf[32][33];
      const int c = tid & 31, r8 = tid >> 5;
      const int tr = bx >> 3, tc = bx & 7;
#pragma unroll
      for (int rr = r8; rr < 32; rr += 8)
        tbuf[rr][c] = f2bf(Vtinv[(tc * 32 + rr) * Hh + tr * 32 + c]);
      __syncthreads();
#pragma unroll
      for (int rr = r8; rr < 32; rr += 8)
        Vtt[(tr * 32 + rr) * Hh + tc * 32 + c] = tbuf[c][rr];
    } else if (bx < 96) {
      const int base = (bx - 64) * 256 + tid;
      const float4 z = {0.f, 0.f, 0.f, 0.f};
#pragma unroll
      for (int it = 0; it < 4; ++it)
        *(float4*)(proj + (size_t)(it * 8192 + base) * 4) = z;
    }
  } else {
    // UinvP: f = tid512*128 + e ; e = ti*32 + tjl*4 + r
    if (bx < 32) {
      const int base = (bx * 256 + tid) * 8;
#pragma unroll
      for (int e8 = 0; e8 < 8; ++e8) {
        int f = base + e8;                  // 0..65535
        int t512 = f >> 7;
        int e = f & 127;
        int ti = e >> 5;
        int rem = e & 31;
        int tjl = rem >> 2;
        int rr = rem & 3;
        int wv = t512 >> 6;
        int ln = t512 & 63;
        int qd = ln >> 4;
        int r15v = ln & 15;
        int i = (wv & 3) * 64 + ti * 16 + qd * 4 + rr;
        int j = (wv >> 2) * 128 + tjl * 16 + r15v;
        UinvP[f] = Uinv[i * Hh + j];
      }
    }
  }
}

// ---------------- kernel 1: fused gates + cell + down-projection -------------
// grid 2048 = b(512) x kb(4); 512 threads = 8 waves; wave owns 32 j-rows
// (R2 decomposition — R3's 4x2 split doubled wf traffic and regressed).
// Chunk-major weights: staging = one contiguous 16B/thread load (8 KB block),
// wf = contiguous 2KB/wave spans. sP aliases the sB dbuf (ph2 combine is
// post-loop, after the final barrier, so sB is dead). LDS 40.4 KB.
// NOTE: no min-waves launch_bounds arg (R1: (512,4) forced VGPR=64 + 2.2 GB
// scratch spill).
__global__ __launch_bounds__(512) void k_main(
    const float* __restrict__ x, const float* __restrict__ hx, const float* __restrict__ cx,
    const u16* __restrict__ RW, const u16* __restrict__ CW, const u16* __restrict__ Vtt,
    const float* __restrict__ bi, const float* __restrict__ bfm, const float* __restrict__ bg,
    const float* __restrict__ UinvP, float* __restrict__ proj) {
  __shared__ union {
    u16 B[2][64][LDSB];   // 18432 B scaled-B dbuf (64 k-rows x 64 t)
    u16 P[256][LDSB];     // 36864 B c-tile (256 j x 64 k)
  } sU;
  __shared__ float sV[KF];        // 1536 B
  __shared__ float sPart[8][64];  // 2048 B

  const int tid  = threadIdx.x;
  const int b    = blockIdx.x >> 2;
  const int kb   = blockIdx.x & 3;
  const int k0   = kb * 64;
  const int lane = tid & 63;
  const int w    = tid >> 6;
  const int r15  = lane & 15;
  const int quad = lane >> 4;

  if (tid < Ii) sV[tid] = x[b * Ii + tid];
  if (tid < Hh) sV[Ii + tid] = hx[b * Hh + tid];

  // phase order: g (tanh), i, f
  const u16* rwp[3] = {RW + 2 * Hh * KF, RW, RW + 1 * Hh * KF};
  const u16* cwp[3] = {CW + 2 * Hh * KF + kb * 24576, CW + kb * 24576,
                       CW + 1 * Hh * KF + kb * 24576};
  const float* bp3[2] = {bg, bi};
  const float* cx_b = cx + (size_t)b * Hh * Hh;

  // prologue: raw chunk 0 load (contiguous, independent of sV)
  U32x4 m;
  m.v = *(const uint4*)(cwp[0] + tid * 8);
  __syncthreads();   // sV ready
  {
    U32x4 o;
    const float4 va = *(const float4*)(&sV[(tid & 7) * 8]);
    const float4 vb = *(const float4*)(&sV[(tid & 7) * 8 + 4]);
    o.d[0] = scale2(m.d[0], va.x, va.y); o.d[1] = scale2(m.d[1], va.z, va.w);
    o.d[2] = scale2(m.d[2], vb.x, vb.y); o.d[3] = scale2(m.d[3], vb.z, vb.w);
    *(uint4*)(&sU.B[0][tid >> 3][(tid & 7) * 8]) = o.v;
  }
  __syncthreads();   // sB[0] ready

  float p[2][4][4];
  f32x4 acc[2][4];
  // wf base: chunk-major row = (w*32 + ja*16 + r15), 64 elems per row
  const int wfoff = (w * 32 + r15) * 64 + quad * 8;

#pragma unroll
  for (int ph = 0; ph < 3; ++ph) {
#pragma unroll
    for (int ja = 0; ja < 2; ++ja)
#pragma unroll
      for (int tk = 0; tk < 4; ++tk)
#pragma unroll
        for (int r = 0; r < 4; ++r) acc[ja][tk][r] = 0.0f;

#pragma unroll
    for (int kc = 0; kc < 6; ++kc) {
      const int sc  = ph * 6 + kc;
      const int cur = sc & 1;
      const int nph = (kc < 5) ? ph : (ph < 2 ? ph + 1 : 0);
      const int nkc = (kc < 5) ? kc + 1 : 0;
      U32x4 mn;
      if (sc < 17)
        mn.v = *(const uint4*)(cwp[nph] + nkc * 4096 + tid * 8);
      bf16x8 wf[2][2];
      {
        const u16* rb = rwp[ph] + kc * 16384 + wfoff;
#pragma unroll
        for (int ja = 0; ja < 2; ++ja)
#pragma unroll
          for (int ks = 0; ks < 2; ++ks)
            wf[ja][ks] = *(const bf16x8*)(rb + ja * 1024 + ks * 32);
      }
#pragma unroll
      for (int ks = 0; ks < 2; ++ks) {
        bf16x8 sf[4];
#pragma unroll
        for (int tk = 0; tk < 4; ++tk)
          sf[tk] = *(const bf16x8*)(&sU.B[cur][tk * 16 + r15][ks * 32 + quad * 8]);
#pragma unroll
        for (int tk = 0; tk < 4; ++tk) {
          acc[0][tk] = __builtin_amdgcn_mfma_f32_16x16x32_bf16(sf[tk], wf[0][ks], acc[0][tk], 0, 0, 0);
          acc[1][tk] = __builtin_amdgcn_mfma_f32_16x16x32_bf16(sf[tk], wf[1][ks], acc[1][tk], 0, 0, 0);
        }
      }
      if (sc < 17) {
        U32x4 o;
        const int nt0 = nkc * 64;
        const float4 va = *(const float4*)(&sV[nt0 + (tid & 7) * 8]);
        const float4 vb = *(const float4*)(&sV[nt0 + (tid & 7) * 8 + 4]);
        o.d[0] = scale2(mn.d[0], va.x, va.y); o.d[1] = scale2(mn.d[1], va.z, va.w);
        o.d[2] = scale2(mn.d[2], vb.x, vb.y); o.d[3] = scale2(mn.d[3], vb.z, vb.w);
        *(uint4*)(&sU.B[cur ^ 1][tid >> 3][(tid & 7) * 8]) = o.v;
      }
      if (ph < 2 && kc == 5) {
        // C layout: row(k) = k0 + tk*16 + quad*4 + r, col(j) = w*32 + ja*16 + r15
        const float* bp = bp3[ph];
#pragma unroll
        for (int ja = 0; ja < 2; ++ja) {
          const int jg = w * 32 + ja * 16 + r15;
          const float* bpr = bp + (size_t)jg * Hh + k0 + quad * 4;
#pragma unroll
          for (int tk = 0; tk < 4; ++tk) {
            const float4 bv = *(const float4*)(bpr + tk * 16);
            if (ph == 0) {
#pragma unroll
              for (int r = 0; r < 4; ++r)
                p[ja][tk][r] = tanh_f(acc[ja][tk][r] + ((const float*)&bv)[r]);
            } else {
#pragma unroll
              for (int r = 0; r < 4; ++r)
                p[ja][tk][r] *= sigm(acc[ja][tk][r] + ((const float*)&bv)[r]);
            }
          }
        }
      }
      __syncthreads();
    }
  }

  // ---- ph2 (f-gate) combine: post final barrier, sU.B dead -> write sU.P ----
#pragma unroll
  for (int ja = 0; ja < 2; ++ja) {
    const int jg = w * 32 + ja * 16 + r15;
    const float* bpr = bfm + (size_t)jg * Hh + k0 + quad * 4;
    const float* cxr = cx_b + (size_t)jg * Hh + k0 + quad * 4;
#pragma unroll
    for (int tk = 0; tk < 4; ++tk) {
      const float4 bv = *(const float4*)(bpr + tk * 16);
      const float4 cv = *(const float4*)(cxr + tk * 16);
      float cc[4];
#pragma unroll
      for (int r = 0; r < 4; ++r)
        cc[r] = sigm(acc[ja][tk][r] + ((const float*)&bv)[r]) * ((const float*)&cv)[r] + p[ja][tk][r];
      uint2 pk;
      pk.x = pack_bf16x2(cc[0], cc[1]);
      pk.y = pack_bf16x2(cc[2], cc[3]);
      *(uint2*)(&sU.P[jg][tk * 16 + quad * 4]) = pk;
    }
  }
  __syncthreads();

  // ---- projection: M[i,j] = sum_k Vtt[i,k] c[j,k]; racc[i] += M[i,j]*Uinv[i,j]
  //      wave: i-slab = (w&3)*64, j-half = (w>>2)*128 .. +128
  const int islab = (w & 3) * 64;
  const int jhb   = (w >> 2) * 128;
  const float* up = UinvP + (size_t)tid * 128;
  float racc[4][4];
#pragma unroll
  for (int ti = 0; ti < 4; ++ti)
#pragma unroll
    for (int r = 0; r < 4; ++r) racc[ti][r] = 0.0f;

#pragma unroll
  for (int tjg = 0; tjg < 2; ++tjg) {
    bf16x8 fbp[2][4];
#pragma unroll
    for (int ks = 0; ks < 2; ++ks)
#pragma unroll
      for (int tjj = 0; tjj < 4; ++tjj)
        fbp[ks][tjj] = *(const bf16x8*)(&sU.P[jhb + (tjg * 4 + tjj) * 16 + r15][ks * 32 + quad * 8]);
#pragma unroll
    for (int ti = 0; ti < 4; ++ti) {
      const u16* vrow = Vtt + (size_t)(islab + ti * 16 + r15) * Hh + k0 + quad * 8;
      const bf16x8 va0 = *(const bf16x8*)vrow;
      const bf16x8 va1 = *(const bf16x8*)(vrow + 32);
      f32x4 pacc[4];
#pragma unroll
      for (int tjj = 0; tjj < 4; ++tjj)
#pragma unroll
        for (int r = 0; r < 4; ++r) pacc[tjj][r] = 0.0f;
#pragma unroll
      for (int tjj = 0; tjj < 4; ++tjj)
        pacc[tjj] = __builtin_amdgcn_mfma_f32_16x16x32_bf16(va0, fbp[0][tjj], pacc[tjj], 0, 0, 0);
#pragma unroll
      for (int tjj = 0; tjj < 4; ++tjj)
        pacc[tjj] = __builtin_amdgcn_mfma_f32_16x16x32_bf16(va1, fbp[1][tjj], pacc[tjj], 0, 0, 0);
#pragma unroll
      for (int tjj = 0; tjj < 4; ++tjj) {
        const float4 uu = *(const float4*)(up + ti * 32 + (tjg * 4 + tjj) * 4);
#pragma unroll
        for (int r = 0; r < 4; ++r)
          racc[ti][r] += pacc[tjj][r] * ((const float*)&uu)[r];
      }
    }
  }

#pragma unroll
  for (int ti = 0; ti < 4; ++ti)
#pragma unroll
    for (int r = 0; r < 4; ++r) {
      float v = racc[ti][r];
      v += __shfl_xor(v, 1);
      v += __shfl_xor(v, 2);
      v += __shfl_xor(v, 4);
      v += __shfl_xor(v, 8);
      if (r15 == 0) sPart[w][ti * 16 + quad * 4 + r] = v;
    }
  __syncthreads();
  if (tid < Hh)
    atomicAdd(&proj[b * Hh + tid], sPart[tid >> 6][tid & 63] + sPart[(tid >> 6) + 4][tid & 63]);
}

// ---------------- kernel 2: o-gate + final output ---------------------------
__global__ __launch_bounds__(256) void k_out(
    const float* __restrict__ x, const float* __restrict__ hx,
    const float* __restrict__ Wio, const float* __restrict__ Who,
    const float* __restrict__ bo, const float* __restrict__ proj,
    float* __restrict__ out) {
  __shared__ float sv[KF];
  const int b = blockIdx.x, tid = threadIdx.x;
  const int lane = tid & 63, w = tid >> 6;
  if (tid < Ii) sv[tid] = x[b * Ii + tid];
  sv[Ii + tid] = hx[b * Hh + tid];
  __syncthreads();
  for (int rr = 0; rr < 64; ++rr) {
    const int h = w * 64 + rr;
    float p = Wio[h * Ii + lane]        * sv[lane]
            + Wio[h * Ii + 64 + lane]   * sv[64 + lane]
            + Who[h * Hh + lane]        * sv[128 + lane]
            + Who[h * Hh + 64 + lane]   * sv[192 + lane]
            + Who[h * Hh + 128 + lane]  * sv[256 + lane]
            + Who[h * Hh + 192 + lane]  * sv[320 + lane];
    p += __shfl_xor(p, 32);
    p += __shfl_xor(p, 16);
    p += __shfl_xor(p, 8);
    p += __shfl_xor(p, 4);
    p += __shfl_xor(p, 2);
    p += __shfl_xor(p, 1);
    if (lane == 0)
      out[b * Hh + h] = sigm(p + bo[h]) * sigm(proj[b * Hh + h]);
  }
}

extern "C" void kernel_launch(void* const* d_in, const int* in_sizes, int n_in,
                              void* d_out, int out_size, void* d_ws, size_t ws_size,
                              hipStream_t stream) {
  (void)in_sizes; (void)n_in; (void)out_size; (void)ws_size;
  const float* x    = (const float*)d_in[0];
  const float* hx   = (const float*)d_in[1];
  const float* cx   = (const float*)d_in[2];
  const float* Wii  = (const float*)d_in[3];
  const float* Wif  = (const float*)d_in[4];
  const float* Wig  = (const float*)d_in[5];
  const float* Wio  = (const float*)d_in[6];
  const float* Whi  = (const float*)d_in[7];
  const float* Whit = (const float*)d_in[8];
  const float* Whf  = (const float*)d_in[9];
  const float* Whft = (const float*)d_in[10];
  const float* Whc  = (const float*)d_in[11];
  const float* Whct = (const float*)d_in[12];
  const float* Who  = (const float*)d_in[13];
  const float* Uinv = (const float*)d_in[14];
  const float* Vtinv= (const float*)d_in[15];
  const float* bi   = (const float*)d_in[16];
  const float* bf   = (const float*)d_in[17];
  const float* bg   = (const float*)d_in[18];
  const float* bo   = (const float*)d_in[19];
  float* out = (float*)d_out;

  // workspace (~2.0 MB): RW[3], CW[3], Vtt (bf16); UinvP, proj (f32)
  u16* RW    = (u16*)d_ws;
  u16* CW    = RW + 3 * Hh * KF;
  u16* Vtt   = CW + 3 * Hh * KF;
  float* UinvP = (float*)(Vtt + Hh * Hh);
  float* proj  = UinvP + Hh * Hh;

  k_prep<<<dim3(96, 5), 256, 0, stream>>>(Wii, Wif, Wig, Whi, Whit, Whf, Whft, Whc, Whct,
                                          Vtinv, Uinv, RW, CW, Vtt, UinvP, proj);
  k_main<<<2048, 512, 0, stream>>>(x, hx, cx, RW, CW, Vtt, bi, bf, bg, UinvP, proj);
  k_out<<<512, 256, 0, stream>>>(x, hx, Wio, Who, bo, proj, out);
}

// Round 6
// 563.115 us; speedup vs baseline: 1.2589x; 1.0275x over previous
//
#include <hip/hip_runtime.h>
#include <hip/hip_bf16.h>

#define Hh 256
#define Ii 128
#define KF 384    // 128 (x) + 256 (hx) feature dim
#define LDSB 72   // padded LDS stride (bf16 elems)

typedef __attribute__((ext_vector_type(8))) short bf16x8;
typedef __attribute__((ext_vector_type(4))) float f32x4;
typedef unsigned short u16;
typedef unsigned int u32;

__device__ inline u16 f2bf(float f) {
  u32 u = __float_as_uint(f);
  u += 0x7FFFu + ((u >> 16) & 1u);   // RNE
  return (u16)(u >> 16);
}
__device__ inline u32 pack_bf16x2(float a, float b) {
  __hip_bfloat162 h = __float22bfloat162_rn(make_float2(a, b));
  u32 r; __builtin_memcpy(&r, &h, 4); return r;
}
// scale packed bf16 pair by (va, vb), repack
__device__ inline u32 scale2(u32 packed, float va, float vb) {
  float lo = __uint_as_float(packed << 16) * va;
  float hi = __uint_as_float(packed & 0xFFFF0000u) * vb;
  return pack_bf16x2(lo, hi);
}
__device__ inline float sigm(float x) { return 1.0f / (1.0f + __expf(-x)); }
__device__ inline float tanh_f(float x) { return 1.0f - 2.0f / (1.0f + __expf(2.0f * x)); }

union U32x4 { bf16x8 f; u32 d[4]; uint4 v; };

// ---------------- kernel 0: pack weights (CHUNK-MAJOR), transpose Vtinv -----
// RWp[ph][kc][j][64]        : ph*98304 + kc*16384 + j*64 + t'
// CWp[ph][kb][kc][k64][64]  : ph*98304 + kb*24576 + kc*4096 + k*64 + t'
__global__ __launch_bounds__(256) void k_prep(
    const float* __restrict__ Wii, const float* __restrict__ Wif, const float* __restrict__ Wig,
    const float* __restrict__ Whi, const float* __restrict__ Whit,
    const float* __restrict__ Whf, const float* __restrict__ Whft,
    const float* __restrict__ Whc, const float* __restrict__ Whct,
    const float* __restrict__ Vtinv, const float* __restrict__ Uinv,
    u16* __restrict__ RW, u16* __restrict__ CW, u16* __restrict__ Vtt,
    float* __restrict__ UinvP, float* __restrict__ proj) {
  const int tid = threadIdx.x, bx = blockIdx.x, y = blockIdx.y;
  if (y < 3) {
    const float* WX  = (y == 0) ? Wii : (y == 1 ? Wif : Wig);
    const float* WHr = (y == 0) ? Whi : (y == 1 ? Whf : Whc);
    const float* WHt = (y == 0) ? Whit : (y == 1 ? Whft : Whct);
    u16* rw = RW + y * Hh * KF;
    u16* cw = CW + y * Hh * KF;
#pragma unroll
    for (int it = 0; it < 4; ++it) {
      int idx = it * 24576 + bx * 256 + tid;   // 0..98303
      int h = idx / KF, t = idx - h * KF;
      float a, c;
      if (t < Ii) { a = WX[h * Ii + t]; c = a; }
      else        { a = WHr[h * Hh + t - Ii]; c = WHt[h * Hh + t - Ii]; }
      rw[(t >> 6) * 16384 + h * 64 + (t & 63)] = f2bf(a);
      cw[(h >> 6) * 24576 + (t >> 6) * 4096 + (h & 63) * 64 + (t & 63)] = f2bf(c);
    }
  } else if (y == 3) {
    if (bx < 64) {
      // Vtt[i][k] = Vtinv[k][i], 32x32 LDS tile transpose
      __shared__ u16 tbuf[32][33];
      const int c = tid & 31, r8 = tid >> 5;
      const int tr = bx >> 3, tc = bx & 7;
#pragma unroll
      for (int rr = r8; rr < 32; rr += 8)
        tbuf[rr][c] = f2bf(Vtinv[(tc * 32 + rr) * Hh + tr * 32 + c]);
      __syncthreads();
#pragma unroll
      for (int rr = r8; rr < 32; rr += 8)
        Vtt[(tr * 32 + rr) * Hh + tc * 32 + c] = tbuf[c][rr];
    } else if (bx < 96) {
      const int base = (bx - 64) * 256 + tid;
      const float4 z = {0.f, 0.f, 0.f, 0.f};
#pragma unroll
      for (int it = 0; it < 4; ++it)
        *(float4*)(proj + (size_t)(it * 8192 + base) * 4) = z;
    }
  } else {
    // UinvP: f = tid512*128 + e ; e = ti*32 + tjl*4 + r
    if (bx < 32) {
      const int base = (bx * 256 + tid) * 8;
#pragma unroll
      for (int e8 = 0; e8 < 8; ++e8) {
        int f = base + e8;                  // 0..65535
        int t512 = f >> 7;
        int e = f & 127;
        int ti = e >> 5;
        int rem = e & 31;
        int tjl = rem >> 2;
        int rr = rem & 3;
        int wv = t512 >> 6;
        int ln = t512 & 63;
        int qd = ln >> 4;
        int r15v = ln & 15;
        int i = (wv & 3) * 64 + ti * 16 + qd * 4 + rr;
        int j = (wv >> 2) * 128 + tjl * 16 + r15v;
        UinvP[f] = Uinv[i * Hh + j];
      }
    }
  }
}

// ---------------- kernel 1: fused gates + cell + down-projection -------------
// grid 2048 = b(512) x kb(4); 512 threads = 8 waves; wave owns 32 j-rows.
// R6: SOFTWARE-PIPELINED register operand loads. R0/R2/R5 all pinned at
// ~370us with every pipe <=25% -> in-interval L2 latency exposure under
// barrier lockstep (all 8 waves park on vmcnt simultaneously, ~1 resident
// block). Fix: wf fragments prefetched at distance 1 (load chunk sc+1
// during sc), staging data at distance 2 (load chunk sc+2 during sc; write
// buffer sc+1 from data loaded during sc-1). All vmcnt waits now sit one
// full interval after issue.
// NOTE: no min-waves launch_bounds arg (R1: (512,4) forced VGPR=64 + 2.2 GB
// scratch spill). Spill tripwire: FETCH_SIZE must stay ~74 MB.
__global__ __launch_bounds__(512) void k_main(
    const float* __restrict__ x, const float* __restrict__ hx, const float* __restrict__ cx,
    const u16* __restrict__ RW, const u16* __restrict__ CW, const u16* __restrict__ Vtt,
    const float* __restrict__ bi, const float* __restrict__ bfm, const float* __restrict__ bg,
    const float* __restrict__ UinvP, float* __restrict__ proj) {
  __shared__ union {
    u16 B[2][64][LDSB];   // 18432 B scaled-B dbuf (64 k-rows x 64 t)
    u16 P[256][LDSB];     // 36864 B c-tile (256 j x 64 k)
  } sU;
  __shared__ float sV[KF];        // 1536 B
  __shared__ float sPart[8][64];  // 2048 B

  const int tid  = threadIdx.x;
  const int b    = blockIdx.x >> 2;
  const int kb   = blockIdx.x & 3;
  const int k0   = kb * 64;
  const int lane = tid & 63;
  const int w    = tid >> 6;
  const int r15  = lane & 15;
  const int quad = lane >> 4;

  if (tid < Ii) sV[tid] = x[b * Ii + tid];
  if (tid < Hh) sV[Ii + tid] = hx[b * Hh + tid];

  // phase order: g (tanh), i, f
  const u16* rwp[3] = {RW + 2 * Hh * KF, RW, RW + 1 * Hh * KF};
  const u16* cwp[3] = {CW + 2 * Hh * KF + kb * 24576, CW + kb * 24576,
                       CW + 1 * Hh * KF + kb * 24576};
  const float* bp3[2] = {bg, bi};
  const float* cx_b = cx + (size_t)b * Hh * Hh;

  // wf base: chunk-major row = (w*32 + ja*16 + r15), 64 elems per row
  const int wfoff = (w * 32 + r15) * 64 + quad * 8;

  // prologue: all chunk-0/1 global loads issue before sV barrier (independent)
  U32x4 m, mnW, mnN;
  bf16x8 wfC[2][2], wfN[2][2];
  m.v   = *(const uint4*)(cwp[0] + tid * 8);            // chunk 0 staging data
  mnW.v = *(const uint4*)(cwp[0] + 4096 + tid * 8);     // chunk 1 staging data
  {
    const u16* rb = rwp[0] + wfoff;                     // chunk 0 fragments
#pragma unroll
    for (int ja = 0; ja < 2; ++ja)
#pragma unroll
      for (int ks = 0; ks < 2; ++ks)
        wfC[ja][ks] = *(const bf16x8*)(rb + ja * 1024 + ks * 32);
  }
  __syncthreads();   // sV ready
  {
    U32x4 o;
    const float4 va = *(const float4*)(&sV[(tid & 7) * 8]);
    const float4 vb = *(const float4*)(&sV[(tid & 7) * 8 + 4]);
    o.d[0] = scale2(m.d[0], va.x, va.y); o.d[1] = scale2(m.d[1], va.z, va.w);
    o.d[2] = scale2(m.d[2], vb.x, vb.y); o.d[3] = scale2(m.d[3], vb.z, vb.w);
    *(uint4*)(&sU.B[0][tid >> 3][(tid & 7) * 8]) = o.v;
  }
  __syncthreads();   // sB[0] ready

  float p[2][4][4];
  f32x4 acc[2][4];

#pragma unroll
  for (int ph = 0; ph < 3; ++ph) {
#pragma unroll
    for (int ja = 0; ja < 2; ++ja)
#pragma unroll
      for (int tk = 0; tk < 4; ++tk)
#pragma unroll
        for (int r = 0; r < 4; ++r) acc[ja][tk][r] = 0.0f;

#pragma unroll
    for (int kc = 0; kc < 6; ++kc) {
      const int sc  = ph * 6 + kc;
      const int cur = sc & 1;
      // prefetch staging data for chunk sc+2 (consumed during interval sc+1)
      if (sc < 16) {
        const int s2 = sc + 2;
        mnN.v = *(const uint4*)(cwp[s2 / 6] + (s2 % 6) * 4096 + tid * 8);
      }
      // prefetch wf fragments for chunk sc+1 (consumed during interval sc+1)
      if (sc < 17) {
        const int s1 = sc + 1;
        const u16* rb = rwp[s1 / 6] + (s1 % 6) * 16384 + wfoff;
#pragma unroll
        for (int ja = 0; ja < 2; ++ja)
#pragma unroll
          for (int ks = 0; ks < 2; ++ks)
            wfN[ja][ks] = *(const bf16x8*)(rb + ja * 1024 + ks * 32);
      }
      // MFMA on current chunk (wfC loaded during interval sc-1: latency hidden)
#pragma unroll
      for (int ks = 0; ks < 2; ++ks) {
        bf16x8 sf[4];
#pragma unroll
        for (int tk = 0; tk < 4; ++tk)
          sf[tk] = *(const bf16x8*)(&sU.B[cur][tk * 16 + r15][ks * 32 + quad * 8]);
#pragma unroll
        for (int tk = 0; tk < 4; ++tk) {
          acc[0][tk] = __builtin_amdgcn_mfma_f32_16x16x32_bf16(sf[tk], wfC[0][ks], acc[0][tk], 0, 0, 0);
          acc[1][tk] = __builtin_amdgcn_mfma_f32_16x16x32_bf16(sf[tk], wfC[1][ks], acc[1][tk], 0, 0, 0);
        }
      }
      // write buffer sc+1 from mnW (loaded during interval sc-1: latency hidden)
      if (sc < 17) {
        U32x4 o;
        const int nt0 = ((sc + 1) % 6) * 64;
        const float4 va = *(const float4*)(&sV[nt0 + (tid & 7) * 8]);
        const float4 vb = *(const float4*)(&sV[nt0 + (tid & 7) * 8 + 4]);
        o.d[0] = scale2(mnW.d[0], va.x, va.y); o.d[1] = scale2(mnW.d[1], va.z, va.w);
        o.d[2] = scale2(mnW.d[2], vb.x, vb.y); o.d[3] = scale2(mnW.d[3], vb.z, vb.w);
        *(uint4*)(&sU.B[cur ^ 1][tid >> 3][(tid & 7) * 8]) = o.v;
      }
      if (ph < 2 && kc == 5) {
        // C layout: row(k) = k0 + tk*16 + quad*4 + r, col(j) = w*32 + ja*16 + r15
        const float* bp = bp3[ph];
#pragma unroll
        for (int ja = 0; ja < 2; ++ja) {
          const int jg = w * 32 + ja * 16 + r15;
          const float* bpr = bp + (size_t)jg * Hh + k0 + quad * 4;
#pragma unroll
          for (int tk = 0; tk < 4; ++tk) {
            const float4 bv = *(const float4*)(bpr + tk * 16);
            if (ph == 0) {
#pragma unroll
              for (int r = 0; r < 4; ++r)
                p[ja][tk][r] = tanh_f(acc[ja][tk][r] + ((const float*)&bv)[r]);
            } else {
#pragma unroll
              for (int r = 0; r < 4; ++r)
                p[ja][tk][r] *= sigm(acc[ja][tk][r] + ((const float*)&bv)[r]);
            }
          }
        }
      }
      __syncthreads();
      // rotate pipeline registers (pure renames under full unroll)
      mnW = mnN;
#pragma unroll
      for (int ja = 0; ja < 2; ++ja)
#pragma unroll
        for (int ks = 0; ks < 2; ++ks)
          wfC[ja][ks] = wfN[ja][ks];
    }
  }

  // ---- ph2 (f-gate) combine: post final barrier, sU.B dead -> write sU.P ----
#pragma unroll
  for (int ja = 0; ja < 2; ++ja) {
    const int jg = w * 32 + ja * 16 + r15;
    const float* bpr = bfm + (size_t)jg * Hh + k0 + quad * 4;
    const float* cxr = cx_b + (size_t)jg * Hh + k0 + quad * 4;
#pragma unroll
    for (int tk = 0; tk < 4; ++tk) {
      const float4 bv = *(const float4*)(bpr + tk * 16);
      const float4 cv = *(const float4*)(cxr + tk * 16);
      float cc[4];
#pragma unroll
      for (int r = 0; r < 4; ++r)
        cc[r] = sigm(acc[ja][tk][r] + ((const float*)&bv)[r]) * ((const float*)&cv)[r] + p[ja][tk][r];
      uint2 pk;
      pk.x = pack_bf16x2(cc[0], cc[1]);
      pk.y = pack_bf16x2(cc[2], cc[3]);
      *(uint2*)(&sU.P[jg][tk * 16 + quad * 4]) = pk;
    }
  }
  __syncthreads();

  // ---- projection: M[i,j] = sum_k Vtt[i,k] c[j,k]; racc[i] += M[i,j]*Uinv[i,j]
  //      wave: i-slab = (w&3)*64, j-half = (w>>2)*128 .. +128
  const int islab = (w & 3) * 64;
  const int jhb   = (w >> 2) * 128;
  const float* up = UinvP + (size_t)tid * 128;
  float racc[4][4];
#pragma unroll
  for (int ti = 0; ti < 4; ++ti)
#pragma unroll
    for (int r = 0; r < 4; ++r) racc[ti][r] = 0.0f;

#pragma unroll
  for (int tjg = 0; tjg < 2; ++tjg) {
    bf16x8 fbp[2][4];
#pragma unroll
    for (int ks = 0; ks < 2; ++ks)
#pragma unroll
      for (int tjj = 0; tjj < 4; ++tjj)
        fbp[ks][tjj] = *(const bf16x8*)(&sU.P[jhb + (tjg * 4 + tjj) * 16 + r15][ks * 32 + quad * 8]);
#pragma unroll
    for (int ti = 0; ti < 4; ++ti) {
      const u16* vrow = Vtt + (size_t)(islab + ti * 16 + r15) * Hh + k0 + quad * 8;
      const bf16x8 va0 = *(const bf16x8*)vrow;
      const bf16x8 va1 = *(const bf16x8*)(vrow + 32);
      f32x4 pacc[4];
#pragma unroll
      for (int tjj = 0; tjj < 4; ++tjj)
#pragma unroll
        for (int r = 0; r < 4; ++r) pacc[tjj][r] = 0.0f;
#pragma unroll
      for (int tjj = 0; tjj < 4; ++tjj)
        pacc[tjj] = __builtin_amdgcn_mfma_f32_16x16x32_bf16(va0, fbp[0][tjj], pacc[tjj], 0, 0, 0);
#pragma unroll
      for (int tjj = 0; tjj < 4; ++tjj)
        pacc[tjj] = __builtin_amdgcn_mfma_f32_16x16x32_bf16(va1, fbp[1][tjj], pacc[tjj], 0, 0, 0);
#pragma unroll
      for (int tjj = 0; tjj < 4; ++tjj) {
        const float4 uu = *(const float4*)(up + ti * 32 + (tjg * 4 + tjj) * 4);
#pragma unroll
        for (int r = 0; r < 4; ++r)
          racc[ti][r] += pacc[tjj][r] * ((const float*)&uu)[r];
      }
    }
  }

#pragma unroll
  for (int ti = 0; ti < 4; ++ti)
#pragma unroll
    for (int r = 0; r < 4; ++r) {
      float v = racc[ti][r];
      v += __shfl_xor(v, 1);
      v += __shfl_xor(v, 2);
      v += __shfl_xor(v, 4);
      v += __shfl_xor(v, 8);
      if (r15 == 0) sPart[w][ti * 16 + quad * 4 + r] = v;
    }
  __syncthreads();
  if (tid < Hh)
    atomicAdd(&proj[b * Hh + tid], sPart[tid >> 6][tid & 63] + sPart[(tid >> 6) + 4][tid & 63]);
}

// ---------------- kernel 2: o-gate + final output ---------------------------
__global__ __launch_bounds__(256) void k_out(
    const float* __restrict__ x, const float* __restrict__ hx,
    const float* __restrict__ Wio, const float* __restrict__ Who,
    const float* __restrict__ bo, const float* __restrict__ proj,
    float* __restrict__ out) {
  __shared__ float sv[KF];
  const int b = blockIdx.x, tid = threadIdx.x;
  const int lane = tid & 63, w = tid >> 6;
  if (tid < Ii) sv[tid] = x[b * Ii + tid];
  sv[Ii + tid] = hx[b * Hh + tid];
  __syncthreads();
  for (int rr = 0; rr < 64; ++rr) {
    const int h = w * 64 + rr;
    float p = Wio[h * Ii + lane]        * sv[lane]
            + Wio[h * Ii + 64 + lane]   * sv[64 + lane]
            + Who[h * Hh + lane]        * sv[128 + lane]
            + Who[h * Hh + 64 + lane]   * sv[192 + lane]
            + Who[h * Hh + 128 + lane]  * sv[256 + lane]
            + Who[h * Hh + 192 + lane]  * sv[320 + lane];
    p += __shfl_xor(p, 32);
    p += __shfl_xor(p, 16);
    p += __shfl_xor(p, 8);
    p += __shfl_xor(p, 4);
    p += __shfl_xor(p, 2);
    p += __shfl_xor(p, 1);
    if (lane == 0)
      out[b * Hh + h] = sigm(p + bo[h]) * sigm(proj[b * Hh + h]);
  }
}

extern "C" void kernel_launch(void* const* d_in, const int* in_sizes, int n_in,
                              void* d_out, int out_size, void* d_ws, size_t ws_size,
                              hipStream_t stream) {
  (void)in_sizes; (void)n_in; (void)out_size; (void)ws_size;
  const float* x    = (const float*)d_in[0];
  const float* hx   = (const float*)d_in[1];
  const float* cx   = (const float*)d_in[2];
  const float* Wii  = (const float*)d_in[3];
  const float* Wif  = (const float*)d_in[4];
  const float* Wig  = (const float*)d_in[5];
  const float* Wio  = (const float*)d_in[6];
  const float* Whi  = (const float*)d_in[7];
  const float* Whit = (const float*)d_in[8];
  const float* Whf  = (const float*)d_in[9];
  const float* Whft = (const float*)d_in[10];
  const float* Whc  = (const float*)d_in[11];
  const float* Whct = (const float*)d_in[12];
  const float* Who  = (const float*)d_in[13];
  const float* Uinv = (const float*)d_in[14];
  const float* Vtinv= (const float*)d_in[15];
  const float* bi   = (const float*)d_in[16];
  const float* bf   = (const float*)d_in[17];
  const float* bg   = (const float*)d_in[18];
  const float* bo   = (const float*)d_in[19];
  float* out = (float*)d_out;

  // workspace (~2.0 MB): RW[3], CW[3], Vtt (bf16); UinvP, proj (f32)
  u16* RW    = (u16*)d_ws;
  u16* CW    = RW + 3 * Hh * KF;
  u16* Vtt   = CW + 3 * Hh * KF;
  float* UinvP = (float*)(Vtt + Hh * Hh);
  float* proj  = UinvP + Hh * Hh;

  k_prep<<<dim3(96, 5), 256, 0, stream>>>(Wii, Wif, Wig, Whi, Whit, Whf, Whft, Whc, Whct,
                                          Vtinv, Uinv, RW, CW, Vtt, UinvP, proj);
  k_main<<<2048, 512, 0, stream>>>(x, hx, cx, RW, CW, Vtt, bi, bf, bg, UinvP, proj);
  k_out<<<512, 256, 0, stream>>>(x, hx, Wio, Who, bo, proj, out);
}

// Round 7
// 521.625 us; speedup vs baseline: 1.3590x; 1.0795x over previous
//
#include <hip/hip_runtime.h>
#include <hip/hip_bf16.h>

#define Hh 256
#define Ii 128
#define KF 384    // 128 (x) + 256 (hx) feature dim
#define LDSB 72   // padded LDS stride (bf16 elems)

typedef __attribute__((ext_vector_type(8))) short bf16x8;
typedef __attribute__((ext_vector_type(4))) float f32x4;
typedef unsigned short u16;
typedef unsigned int u32;

__device__ inline u16 f2bf(float f) {
  u32 u = __float_as_uint(f);
  u += 0x7FFFu + ((u >> 16) & 1u);   // RNE
  return (u16)(u >> 16);
}
__device__ inline u32 pack_bf16x2(float a, float b) {
  __hip_bfloat162 h = __float22bfloat162_rn(make_float2(a, b));
  u32 r; __builtin_memcpy(&r, &h, 4); return r;
}
// scale packed bf16 pair by (va, vb), repack
__device__ inline u32 scale2(u32 packed, float va, float vb) {
  float lo = __uint_as_float(packed << 16) * va;
  float hi = __uint_as_float(packed & 0xFFFF0000u) * vb;
  return pack_bf16x2(lo, hi);
}
__device__ inline float sigm(float x) { return 1.0f / (1.0f + __expf(-x)); }
__device__ inline float tanh_f(float x) { return 1.0f - 2.0f / (1.0f + __expf(2.0f * x)); }

union U32x4 { bf16x8 f; u32 d[4]; uint4 v; };

// ---------------- kernel 0: pack weights (gather / coalesced-store) ---------
// R7 rewrite: every thread owns 8/12/16 consecutive OUTPUT elements, computes
// the inverse index map (shifts + one const-div), loads contiguous float4s,
// stores coalesced uint4s. Old version was output-scattered with an integer
// divide per element. Also emits WoT[t][h] (transposed o-gate weights) for
// the rewritten k_out.
// Layouts (unchanged): RWp[ph][kc][j][64] ; CWp[ph][kb][kc][k64][64]
__global__ __launch_bounds__(256) void k_prep(
    const float* __restrict__ Wii, const float* __restrict__ Wif, const float* __restrict__ Wig,
    const float* __restrict__ Whi, const float* __restrict__ Whit,
    const float* __restrict__ Whf, const float* __restrict__ Whft,
    const float* __restrict__ Whc, const float* __restrict__ Whct,
    const float* __restrict__ Vtinv, const float* __restrict__ Uinv,
    const float* __restrict__ Wio, const float* __restrict__ Who,
    u16* __restrict__ RW, u16* __restrict__ CW, u16* __restrict__ Vtt,
    float* __restrict__ UinvP, float* __restrict__ proj, float* __restrict__ WoT) {
  const int tid = threadIdx.x, bx = blockIdx.x, y = blockIdx.y;
  if (y < 3) {
    // RW phase y: f = kc*16384 + h*64 + t0 ; t = kc*64 + t0
    if (bx < 48) {
      const float* WX  = (y == 0) ? Wii : (y == 1 ? Wif : Wig);
      const float* WHr = (y == 0) ? Whi : (y == 1 ? Whf : Whc);
      u16* rw = RW + y * Hh * KF;
      const int f  = (bx * 256 + tid) * 8;
      const int kc = f >> 14;
      const int h  = (f >> 6) & 255;
      const int t0 = f & 63;
      const float* src = (kc < 2) ? (WX + h * Ii + kc * 64 + t0)
                                  : (WHr + h * Hh + (kc - 2) * 64 + t0);
      const float4 s0 = *(const float4*)src;
      const float4 s1 = *(const float4*)(src + 4);
      uint4 o;
      o.x = (u32)f2bf(s0.x) | ((u32)f2bf(s0.y) << 16);
      o.y = (u32)f2bf(s0.z) | ((u32)f2bf(s0.w) << 16);
      o.z = (u32)f2bf(s1.x) | ((u32)f2bf(s1.y) << 16);
      o.w = (u32)f2bf(s1.z) | ((u32)f2bf(s1.w) << 16);
      *(uint4*)(rw + f) = o;
    }
  } else if (y < 6) {
    // CW phase y-3: f = kb*24576 + kc*4096 + k*64 + t0 ; h = kb*64+k
    if (bx < 48) {
      const int ph = y - 3;
      const float* WX  = (ph == 0) ? Wii : (ph == 1 ? Wif : Wig);
      const float* WHt = (ph == 0) ? Whit : (ph == 1 ? Whft : Whct);
      u16* cw = CW + ph * Hh * KF;
      const int f  = (bx * 256 + tid) * 8;
      const int kb = f / 24576;
      const int r  = f - kb * 24576;
      const int kc = r >> 12;
      const int r2 = r & 4095;
      const int k  = r2 >> 6;
      const int t0 = r2 & 63;
      const int h  = kb * 64 + k;
      const float* src = (kc < 2) ? (WX + h * Ii + kc * 64 + t0)
                                  : (WHt + h * Hh + (kc - 2) * 64 + t0);
      const float4 s0 = *(const float4*)src;
      const float4 s1 = *(const float4*)(src + 4);
      uint4 o;
      o.x = (u32)f2bf(s0.x) | ((u32)f2bf(s0.y) << 16);
      o.y = (u32)f2bf(s0.z) | ((u32)f2bf(s0.w) << 16);
      o.z = (u32)f2bf(s1.x) | ((u32)f2bf(s1.y) << 16);
      o.w = (u32)f2bf(s1.z) | ((u32)f2bf(s1.w) << 16);
      *(uint4*)(cw + f) = o;
    }
  } else if (y == 6) {
    if (bx < 64) {
      // Vtt[i][k] = Vtinv[k][i], 32x32 LDS tile transpose
      __shared__ u16 tbuf[32][33];
      const int c = tid & 31, r8 = tid >> 5;
      const int tr = bx >> 3, tc = bx & 7;
#pragma unroll
      for (int rr = r8; rr < 32; rr += 8)
        tbuf[rr][c] = f2bf(Vtinv[(tc * 32 + rr) * Hh + tr * 32 + c]);
      __syncthreads();
#pragma unroll
      for (int rr = r8; rr < 32; rr += 8)
        Vtt[(tr * 32 + rr) * Hh + tc * 32 + c] = tbuf[c][rr];
    } else {
      // WoT[t][h] = o-gate weight (h,t): coalesced writes across tid=h
      const int tb = (bx - 64) * 12;
#pragma unroll
      for (int tt = 0; tt < 12; ++tt) {
        const int t = tb + tt;
        const float v = (t < Ii) ? Wio[tid * Ii + t] : Who[tid * Hh + t - Ii];
        WoT[t * Hh + tid] = v;
      }
    }
  } else {
    if (bx < 32) {
      // UinvP: f = tid512*128 + e ; e = ti*32 + tjl*4 + r
      const int base = (bx * 256 + tid) * 8;
#pragma unroll
      for (int e8 = 0; e8 < 8; ++e8) {
        int f = base + e8;                  // 0..65535
        int t512 = f >> 7;
        int e = f & 127;
        int ti = e >> 5;
        int rem = e & 31;
        int tjl = rem >> 2;
        int rr = rem & 3;
        int wv = t512 >> 6;
        int ln = t512 & 63;
        int qd = ln >> 4;
        int r15v = ln & 15;
        int i = (wv & 3) * 64 + ti * 16 + qd * 4 + rr;
        int j = (wv >> 2) * 128 + tjl * 16 + r15v;
        UinvP[f] = Uinv[i * Hh + j];
      }
    } else if (bx < 64) {
      const int base = (bx - 32) * 256 + tid;
      const float4 z = {0.f, 0.f, 0.f, 0.f};
#pragma unroll
      for (int it = 0; it < 4; ++it)
        *(float4*)(proj + (size_t)(it * 8192 + base) * 4) = z;
    }
  }
}

// ---------------- kernel 1: fused gates + cell + down-projection -------------
// (byte-identical to R6: pipelined register loads, chunk-major weights.
//  k_main has asymptoted at ~351us; this round targets k_prep/k_out.)
__global__ __launch_bounds__(512) void k_main(
    const float* __restrict__ x, const float* __restrict__ hx, const float* __restrict__ cx,
    const u16* __restrict__ RW, const u16* __restrict__ CW, const u16* __restrict__ Vtt,
    const float* __restrict__ bi, const float* __restrict__ bfm, const float* __restrict__ bg,
    const float* __restrict__ UinvP, float* __restrict__ proj) {
  __shared__ union {
    u16 B[2][64][LDSB];   // 18432 B scaled-B dbuf (64 k-rows x 64 t)
    u16 P[256][LDSB];     // 36864 B c-tile (256 j x 64 k)
  } sU;
  __shared__ float sV[KF];        // 1536 B
  __shared__ float sPart[8][64];  // 2048 B

  const int tid  = threadIdx.x;
  const int b    = blockIdx.x >> 2;
  const int kb   = blockIdx.x & 3;
  const int k0   = kb * 64;
  const int lane = tid & 63;
  const int w    = tid >> 6;
  const int r15  = lane & 15;
  const int quad = lane >> 4;

  if (tid < Ii) sV[tid] = x[b * Ii + tid];
  if (tid < Hh) sV[Ii + tid] = hx[b * Hh + tid];

  // phase order: g (tanh), i, f
  const u16* rwp[3] = {RW + 2 * Hh * KF, RW, RW + 1 * Hh * KF};
  const u16* cwp[3] = {CW + 2 * Hh * KF + kb * 24576, CW + kb * 24576,
                       CW + 1 * Hh * KF + kb * 24576};
  const float* bp3[2] = {bg, bi};
  const float* cx_b = cx + (size_t)b * Hh * Hh;

  // wf base: chunk-major row = (w*32 + ja*16 + r15), 64 elems per row
  const int wfoff = (w * 32 + r15) * 64 + quad * 8;

  // prologue: all chunk-0/1 global loads issue before sV barrier (independent)
  U32x4 m, mnW, mnN;
  bf16x8 wfC[2][2], wfN[2][2];
  m.v   = *(const uint4*)(cwp[0] + tid * 8);            // chunk 0 staging data
  mnW.v = *(const uint4*)(cwp[0] + 4096 + tid * 8);     // chunk 1 staging data
  {
    const u16* rb = rwp[0] + wfoff;                     // chunk 0 fragments
#pragma unroll
    for (int ja = 0; ja < 2; ++ja)
#pragma unroll
      for (int ks = 0; ks < 2; ++ks)
        wfC[ja][ks] = *(const bf16x8*)(rb + ja * 1024 + ks * 32);
  }
  __syncthreads();   // sV ready
  {
    U32x4 o;
    const float4 va = *(const float4*)(&sV[(tid & 7) * 8]);
    const float4 vb = *(const float4*)(&sV[(tid & 7) * 8 + 4]);
    o.d[0] = scale2(m.d[0], va.x, va.y); o.d[1] = scale2(m.d[1], va.z, va.w);
    o.d[2] = scale2(m.d[2], vb.x, vb.y); o.d[3] = scale2(m.d[3], vb.z, vb.w);
    *(uint4*)(&sU.B[0][tid >> 3][(tid & 7) * 8]) = o.v;
  }
  __syncthreads();   // sB[0] ready

  float p[2][4][4];
  f32x4 acc[2][4];

#pragma unroll
  for (int ph = 0; ph < 3; ++ph) {
#pragma unroll
    for (int ja = 0; ja < 2; ++ja)
#pragma unroll
      for (int tk = 0; tk < 4; ++tk)
#pragma unroll
        for (int r = 0; r < 4; ++r) acc[ja][tk][r] = 0.0f;

#pragma unroll
    for (int kc = 0; kc < 6; ++kc) {
      const int sc  = ph * 6 + kc;
      const int cur = sc & 1;
      // prefetch staging data for chunk sc+2 (consumed during interval sc+1)
      if (sc < 16) {
        const int s2 = sc + 2;
        mnN.v = *(const uint4*)(cwp[s2 / 6] + (s2 % 6) * 4096 + tid * 8);
      }
      // prefetch wf fragments for chunk sc+1 (consumed during interval sc+1)
      if (sc < 17) {
        const int s1 = sc + 1;
        const u16* rb = rwp[s1 / 6] + (s1 % 6) * 16384 + wfoff;
#pragma unroll
        for (int ja = 0; ja < 2; ++ja)
#pragma unroll
          for (int ks = 0; ks < 2; ++ks)
            wfN[ja][ks] = *(const bf16x8*)(rb + ja * 1024 + ks * 32);
      }
      // MFMA on current chunk (wfC loaded during interval sc-1: latency hidden)
#pragma unroll
      for (int ks = 0; ks < 2; ++ks) {
        bf16x8 sf[4];
#pragma unroll
        for (int tk = 0; tk < 4; ++tk)
          sf[tk] = *(const bf16x8*)(&sU.B[cur][tk * 16 + r15][ks * 32 + quad * 8]);
#pragma unroll
        for (int tk = 0; tk < 4; ++tk) {
          acc[0][tk] = __builtin_amdgcn_mfma_f32_16x16x32_bf16(sf[tk], wfC[0][ks], acc[0][tk], 0, 0, 0);
          acc[1][tk] = __builtin_amdgcn_mfma_f32_16x16x32_bf16(sf[tk], wfC[1][ks], acc[1][tk], 0, 0, 0);
        }
      }
      // write buffer sc+1 from mnW (loaded during interval sc-1: latency hidden)
      if (sc < 17) {
        U32x4 o;
        const int nt0 = ((sc + 1) % 6) * 64;
        const float4 va = *(const float4*)(&sV[nt0 + (tid & 7) * 8]);
        const float4 vb = *(const float4*)(&sV[nt0 + (tid & 7) * 8 + 4]);
        o.d[0] = scale2(mnW.d[0], va.x, va.y); o.d[1] = scale2(mnW.d[1], va.z, va.w);
        o.d[2] = scale2(mnW.d[2], vb.x, vb.y); o.d[3] = scale2(mnW.d[3], vb.z, vb.w);
        *(uint4*)(&sU.B[cur ^ 1][tid >> 3][(tid & 7) * 8]) = o.v;
      }
      if (ph < 2 && kc == 5) {
        // C layout: row(k) = k0 + tk*16 + quad*4 + r, col(j) = w*32 + ja*16 + r15
        const float* bp = bp3[ph];
#pragma unroll
        for (int ja = 0; ja < 2; ++ja) {
          const int jg = w * 32 + ja * 16 + r15;
          const float* bpr = bp + (size_t)jg * Hh + k0 + quad * 4;
#pragma unroll
          for (int tk = 0; tk < 4; ++tk) {
            const float4 bv = *(const float4*)(bpr + tk * 16);
            if (ph == 0) {
#pragma unroll
              for (int r = 0; r < 4; ++r)
                p[ja][tk][r] = tanh_f(acc[ja][tk][r] + ((const float*)&bv)[r]);
            } else {
#pragma unroll
              for (int r = 0; r < 4; ++r)
                p[ja][tk][r] *= sigm(acc[ja][tk][r] + ((const float*)&bv)[r]);
            }
          }
        }
      }
      __syncthreads();
      // rotate pipeline registers (pure renames under full unroll)
      mnW = mnN;
#pragma unroll
      for (int ja = 0; ja < 2; ++ja)
#pragma unroll
        for (int ks = 0; ks < 2; ++ks)
          wfC[ja][ks] = wfN[ja][ks];
    }
  }

  // ---- ph2 (f-gate) combine: post final barrier, sU.B dead -> write sU.P ----
#pragma unroll
  for (int ja = 0; ja < 2; ++ja) {
    const int jg = w * 32 + ja * 16 + r15;
    const float* bpr = bfm + (size_t)jg * Hh + k0 + quad * 4;
    const float* cxr = cx_b + (size_t)jg * Hh + k0 + quad * 4;
#pragma unroll
    for (int tk = 0; tk < 4; ++tk) {
      const float4 bv = *(const float4*)(bpr + tk * 16);
      const float4 cv = *(const float4*)(cxr + tk * 16);
      float cc[4];
#pragma unroll
      for (int r = 0; r < 4; ++r)
        cc[r] = sigm(acc[ja][tk][r] + ((const float*)&bv)[r]) * ((const float*)&cv)[r] + p[ja][tk][r];
      uint2 pk;
      pk.x = pack_bf16x2(cc[0], cc[1]);
      pk.y = pack_bf16x2(cc[2], cc[3]);
      *(uint2*)(&sU.P[jg][tk * 16 + quad * 4]) = pk;
    }
  }
  __syncthreads();

  // ---- projection: M[i,j] = sum_k Vtt[i,k] c[j,k]; racc[i] += M[i,j]*Uinv[i,j]
  //      wave: i-slab = (w&3)*64, j-half = (w>>2)*128 .. +128
  const int islab = (w & 3) * 64;
  const int jhb   = (w >> 2) * 128;
  const float* up = UinvP + (size_t)tid * 128;
  float racc[4][4];
#pragma unroll
  for (int ti = 0; ti < 4; ++ti)
#pragma unroll
    for (int r = 0; r < 4; ++r) racc[ti][r] = 0.0f;

#pragma unroll
  for (int tjg = 0; tjg < 2; ++tjg) {
    bf16x8 fbp[2][4];
#pragma unroll
    for (int ks = 0; ks < 2; ++ks)
#pragma unroll
      for (int tjj = 0; tjj < 4; ++tjj)
        fbp[ks][tjj] = *(const bf16x8*)(&sU.P[jhb + (tjg * 4 + tjj) * 16 + r15][ks * 32 + quad * 8]);
#pragma unroll
    for (int ti = 0; ti < 4; ++ti) {
      const u16* vrow = Vtt + (size_t)(islab + ti * 16 + r15) * Hh + k0 + quad * 8;
      const bf16x8 va0 = *(const bf16x8*)vrow;
      const bf16x8 va1 = *(const bf16x8*)(vrow + 32);
      f32x4 pacc[4];
#pragma unroll
      for (int tjj = 0; tjj < 4; ++tjj)
#pragma unroll
        for (int r = 0; r < 4; ++r) pacc[tjj][r] = 0.0f;
#pragma unroll
      for (int tjj = 0; tjj < 4; ++tjj)
        pacc[tjj] = __builtin_amdgcn_mfma_f32_16x16x32_bf16(va0, fbp[0][tjj], pacc[tjj], 0, 0, 0);
#pragma unroll
      for (int tjj = 0; tjj < 4; ++tjj)
        pacc[tjj] = __builtin_amdgcn_mfma_f32_16x16x32_bf16(va1, fbp[1][tjj], pacc[tjj], 0, 0, 0);
#pragma unroll
      for (int tjj = 0; tjj < 4; ++tjj) {
        const float4 uu = *(const float4*)(up + ti * 32 + (tjg * 4 + tjj) * 4);
#pragma unroll
        for (int r = 0; r < 4; ++r)
          racc[ti][r] += pacc[tjj][r] * ((const float*)&uu)[r];
      }
    }
  }

#pragma unroll
  for (int ti = 0; ti < 4; ++ti)
#pragma unroll
    for (int r = 0; r < 4; ++r) {
      float v = racc[ti][r];
      v += __shfl_xor(v, 1);
      v += __shfl_xor(v, 2);
      v += __shfl_xor(v, 4);
      v += __shfl_xor(v, 8);
      if (r15 == 0) sPart[w][ti * 16 + quad * 4 + r] = v;
    }
  __syncthreads();
  if (tid < Hh)
    atomicAdd(&proj[b * Hh + tid], sPart[tid >> 6][tid & 63] + sPart[(tid >> 6) + 4][tid & 63]);
}

// ---------------- kernel 2: o-gate + final output ---------------------------
// R7 rewrite: one thread per (b,h). Coalesced WoT[t][h] column reads (lane h
// consecutive) + LDS-broadcast sv[t], unroll 16 for load ILP. Replaces the
// serial 64-iteration shuffle-reduce chain (6-deep dependent shfl per iter).
__global__ __launch_bounds__(256) void k_out(
    const float* __restrict__ x, const float* __restrict__ hx,
    const float* __restrict__ WoT, const float* __restrict__ bo,
    const float* __restrict__ proj, float* __restrict__ out) {
  __shared__ float sv[KF];
  const int b = blockIdx.x, tid = threadIdx.x;
  if (tid < Ii) sv[tid] = x[b * Ii + tid];
  sv[Ii + tid] = hx[b * Hh + tid];
  __syncthreads();
  float acc = 0.0f;
  const float* wp = WoT + tid;
#pragma unroll 16
  for (int t = 0; t < KF; ++t)
    acc = fmaf(sv[t], wp[(size_t)t * Hh], acc);
  out[b * Hh + tid] = sigm(acc + bo[tid]) * sigm(proj[b * Hh + tid]);
}

extern "C" void kernel_launch(void* const* d_in, const int* in_sizes, int n_in,
                              void* d_out, int out_size, void* d_ws, size_t ws_size,
                              hipStream_t stream) {
  (void)in_sizes; (void)n_in; (void)out_size; (void)ws_size;
  const float* x    = (const float*)d_in[0];
  const float* hx   = (const float*)d_in[1];
  const float* cx   = (const float*)d_in[2];
  const float* Wii  = (const float*)d_in[3];
  const float* Wif  = (const float*)d_in[4];
  const float* Wig  = (const float*)d_in[5];
  const float* Wio  = (const float*)d_in[6];
  const float* Whi  = (const float*)d_in[7];
  const float* Whit = (const float*)d_in[8];
  const float* Whf  = (const float*)d_in[9];
  const float* Whft = (const float*)d_in[10];
  const float* Whc  = (const float*)d_in[11];
  const float* Whct = (const float*)d_in[12];
  const float* Who  = (const float*)d_in[13];
  const float* Uinv = (const float*)d_in[14];
  const float* Vtinv= (const float*)d_in[15];
  const float* bi   = (const float*)d_in[16];
  const float* bf   = (const float*)d_in[17];
  const float* bg   = (const float*)d_in[18];
  const float* bo   = (const float*)d_in[19];
  float* out = (float*)d_out;

  // workspace (2,490,368 B): RW[3], CW[3], Vtt (bf16); UinvP, proj, WoT (f32)
  u16* RW    = (u16*)d_ws;
  u16* CW    = RW + 3 * Hh * KF;          // u16 idx 294912
  u16* Vtt   = CW + 3 * Hh * KF;          // u16 idx 589824
  float* UinvP = (float*)(Vtt + Hh * Hh); // byte 1,310,720
  float* proj  = UinvP + Hh * Hh;         // byte 1,572,864
  float* WoT   = proj + 512 * Hh;         // byte 2,097,152 (+393,216 = 2,490,368)

  k_prep<<<dim3(96, 8), 256, 0, stream>>>(Wii, Wif, Wig, Whi, Whit, Whf, Whft, Whc, Whct,
                                          Vtinv, Uinv, Wio, Who,
                                          RW, CW, Vtt, UinvP, proj, WoT);
  k_main<<<2048, 512, 0, stream>>>(x, hx, cx, RW, CW, Vtt, bi, bf, bg, UinvP, proj);
  k_out<<<512, 256, 0, stream>>>(x, hx, WoT, bo, proj, out);
}